// Round 5
// baseline (221.316 us; speedup 1.0000x reference)
//
#include <hip/hip_runtime.h>
#include <math.h>

#define H 1024
#define V 50257
#define S 2048
#define NCH 64             // attention chunks (32 s-rows each)
#define GRID 6283          // mega grid: 8 logit rows per block
#define TPRE 512           // prelude ticket blocks

// ws float offsets
#define O_CTXP   0                    // NCH*H = 65536
#define O_CTX    65536                // H
#define O_Z      66560                // H
#define O_HNEW   67584                // H
#define O_PART   68608                // 2*GRID = 12566
#define O_LOGITS 81174                // V  (scalar access only)

// Persistent device state: zero-initialized at module load. Monotonic across
// graph replays; epoch arithmetic (r = ticket/GRID) makes every launch see
// consistent barrier targets without any reset/init kernel.
__device__ unsigned g_ticket;
__device__ unsigned g_sync[64];       // counters at [0],[16],[32],[48] (separate lines)

__device__ inline float wred_sum(float v) {
    for (int o = 32; o > 0; o >>= 1) v += __shfl_down(v, o, 64);
    return v;
}
__device__ inline float sigm(float x) { return 1.f / (1.f + expf(-x)); }
__device__ inline float dot4(float4 a, float4 b) {
    return a.x*b.x + a.y*b.y + a.z*b.z + a.w*b.w;
}

// release: block's writes -> device scope, then count arrival
__device__ inline void sig(unsigned* c) {
    __syncthreads();
    if (threadIdx.x == 0) {
        __threadfence();
        __hip_atomic_fetch_add(c, 1u, __ATOMIC_RELEASE, __HIP_MEMORY_SCOPE_AGENT);
    }
}
// relaxed polling (no per-poll cache invalidate), single acquire fence on exit
template<int SLP>
__device__ inline void waitc(unsigned* c, unsigned target) {
    if (threadIdx.x == 0) {
        while ((int)(__hip_atomic_load(c, __ATOMIC_RELAXED, __HIP_MEMORY_SCOPE_AGENT) - target) < 0)
            __builtin_amdgcn_s_sleep(SLP);
        __builtin_amdgcn_fence(__ATOMIC_ACQUIRE, "agent");
    }
    __syncthreads();
}

__global__ __launch_bounds__(256, 4) void mega(
    const int* __restrict__ ids, const float* __restrict__ h0,
    const float* __restrict__ c0, const float* __restrict__ enc,
    const float* __restrict__ emb, const float* __restrict__ attn_W,
    const float* __restrict__ attn_b, const float* __restrict__ comb_W,
    const float* __restrict__ comb_b, const float* __restrict__ W_ih,
    const float* __restrict__ W_hh, const float* __restrict__ b_ih,
    const float* __restrict__ b_hh, const float* __restrict__ out_W,
    const float* __restrict__ out_b, float* __restrict__ out,
    float* __restrict__ ws)
{
    const int t = threadIdx.x, lane = t & 63, wave = t >> 6;
    __shared__ unsigned stk;
    __shared__ float sred[8];
    __shared__ float scoef[32];
    __shared__ float slg[8];

    if (t == 0)
        stk = __hip_atomic_fetch_add(&g_ticket, 1u, __ATOMIC_RELAXED,
                                     __HIP_MEMORY_SCOPE_AGENT);
    __syncthreads();
    const unsigned tg = stk;
    const unsigned r  = tg / GRID;          // replay epoch
    const unsigned tk = tg - r * GRID;      // arrival-order ticket within launch
    unsigned* cA  = &g_sync[0];
    unsigned* cA2 = &g_sync[16];
    unsigned* cB  = &g_sync[32];
    unsigned* cC  = &g_sync[48];

    // ================= prelude (first-arriving TPRE blocks) =================
    if (tk < NCH) {
        // ---- A: chunk tk = 32 enc rows: hdot + coeff (LDS) + ctxp partial ----
        float4 hv4 = ((const float4*)h0)[t];
        float4 wv4 = ((const float4*)(attn_W + H))[t];
        float p = wred_sum(dot4(hv4, wv4));
        if (lane == 0) sred[wave] = p;
        __syncthreads();
        const float hdot = sred[0] + sred[1] + sred[2] + sred[3] + attn_b[0];
        const float4* w0 = (const float4*)attn_W;
        const int s0 = tk * 32;
        #pragma unroll
        for (int gq = 0; gq < 2; ++gq) {
            int sb = s0 + wave * 8 + gq * 4;
            const float4* e0 = (const float4*)(enc + (size_t)(sb    ) * H);
            const float4* e1 = (const float4*)(enc + (size_t)(sb + 1) * H);
            const float4* e2 = (const float4*)(enc + (size_t)(sb + 2) * H);
            const float4* e3 = (const float4*)(enc + (size_t)(sb + 3) * H);
            float a0 = 0.f, a1 = 0.f, a2 = 0.f, a3 = 0.f;
            #pragma unroll
            for (int kk = 0; kk < 4; ++kk) {
                int k4 = kk * 64 + lane;
                float4 w = w0[k4];
                a0 += dot4(e0[k4], w); a1 += dot4(e1[k4], w);
                a2 += dot4(e2[k4], w); a3 += dot4(e3[k4], w);
            }
            a0 = wred_sum(a0); a1 = wred_sum(a1);
            a2 = wred_sum(a2); a3 = wred_sum(a3);
            if (lane == 0) {
                scoef[wave*8 + gq*4 + 0] = a0 + hdot;
                scoef[wave*8 + gq*4 + 1] = a1 + hdot;
                scoef[wave*8 + gq*4 + 2] = a2 + hdot;
                scoef[wave*8 + gq*4 + 3] = a3 + hdot;
            }
        }
        __syncthreads();
        float4 a4 = make_float4(0.f, 0.f, 0.f, 0.f);
        #pragma unroll 8
        for (int rr = 0; rr < 32; ++rr) {
            float c = scoef[rr];
            float4 e = ((const float4*)(enc + (size_t)(s0 + rr) * H))[t];
            a4.x += c * e.x; a4.y += c * e.y; a4.z += c * e.z; a4.w += c * e.w;
        }
        ((float4*)(ws + O_CTXP + tk * H))[t] = a4;
        sig(cA);
        waitc<4>(cA, r * NCH + NCH);
        // ---- A2: ctx[j] = sum over 64 chunks, j in [tk*16, tk*16+16) ----
        #pragma unroll
        for (int q = 0; q < 4; ++q) {
            int j = tk * 16 + wave * 4 + q;
            float v = wred_sum(ws[O_CTXP + lane * H + j]);
            if (lane == 0) ws[O_CTX + j] = v;
        }
        sig(cA2);
    }
    if (tk < 256) {
        waitc<4>(cA2, r * NCH + NCH);
        // ---- B: z row i = tk*4 + wave ----
        const int tok = ids[0];
        const int i = tk * 4 + wave;
        const float4* wrow = (const float4*)(comb_W + (size_t)i * 2 * H);
        const float4* x4 = (const float4*)(emb + (size_t)tok * H);
        const float4* c4 = (const float4*)(ws + O_CTX);
        float acc = 0.f;
        #pragma unroll
        for (int kk = 0; kk < 4; ++kk) {
            int k4 = kk * 64 + lane;
            acc += dot4(wrow[k4], x4[k4]);
            acc += dot4(wrow[256 + k4], c4[k4]);
        }
        acc = wred_sum(acc);
        if (lane == 0) ws[O_Z + i] = fmaxf(acc + comb_b[i], 0.f);
        sig(cB);
    }
    if (tk < TPRE) {
        waitc<4>(cB, r * 256 + 256);
        // ---- C: gates for j0=2tk, j1=2tk+1; wave = gate (i,f,g,o) ----
        const int j0 = tk * 2;
        const int row0 = wave * H + j0, row1 = row0 + 1;
        const float4* wi0 = (const float4*)(W_ih + (size_t)row0 * H);
        const float4* wi1 = (const float4*)(W_ih + (size_t)row1 * H);
        const float4* wh0 = (const float4*)(W_hh + (size_t)row0 * H);
        const float4* wh1 = (const float4*)(W_hh + (size_t)row1 * H);
        const float4* zv = (const float4*)(ws + O_Z);
        const float4* hv = (const float4*)h0;
        float acc0 = 0.f, acc1 = 0.f;
        #pragma unroll
        for (int kk = 0; kk < 4; ++kk) {
            int k4 = kk * 64 + lane;
            float4 z4 = zv[k4], h4 = hv[k4];
            acc0 += dot4(wi0[k4], z4) + dot4(wh0[k4], h4);
            acc1 += dot4(wi1[k4], z4) + dot4(wh1[k4], h4);
        }
        acc0 = wred_sum(acc0); acc1 = wred_sum(acc1);
        if (lane == 0) {
            sred[wave * 2    ] = acc0 + b_ih[row0] + b_hh[row0];
            sred[wave * 2 + 1] = acc1 + b_ih[row1] + b_hh[row1];
        }
        __syncthreads();
        if (t < 2) {
            int j = j0 + t;
            float ig = sigm(sred[0 + t]);
            float fg = sigm(sred[2 + t]);
            float gg = tanhf(sred[4 + t]);
            float og = sigm(sred[6 + t]);
            float cn = fg * c0[j] + ig * gg;
            float hn = og * tanhf(cn);
            out[V + j]     = hn;
            out[V + H + j] = cn;
            ws[O_HNEW + j] = hn;
        }
        sig(cC);
        waitc<4>(cC, r * TPRE + TPRE);
    } else {
        waitc<64>(cC, r * TPRE + TPRE);
    }

    // ================= logits GEMV (all blocks, by blockIdx) =================
    {
        const float4* hv = (const float4*)(ws + O_HNEW);
        float4 hr[4];
        #pragma unroll
        for (int kk = 0; kk < 4; ++kk) hr[kk] = hv[kk * 64 + lane];
        const int v0 = blockIdx.x * 8 + wave * 2;
        const int v1 = v0 + 1;
        const bool q0 = v0 < V, q1 = v1 < V;
        const float4* w0r = (const float4*)(out_W + (size_t)(q0 ? v0 : 0) * H);
        const float4* w1r = (const float4*)(out_W + (size_t)(q1 ? v1 : 0) * H);
        float acc0 = 0.f, acc1 = 0.f;
        #pragma unroll
        for (int kk = 0; kk < 4; ++kk) {
            int k4 = kk * 64 + lane;
            float4 a = hr[kk];
            acc0 += dot4(w0r[k4], a);
            acc1 += dot4(w1r[k4], a);
        }
        acc0 = wred_sum(acc0); acc1 = wred_sum(acc1);
        if (lane == 0) {
            float l0 = acc0 + out_b[q0 ? v0 : 0];
            float l1 = acc1 + out_b[q1 ? v1 : 0];
            if (q0) ws[O_LOGITS + v0] = l0;
            if (q1) ws[O_LOGITS + v1] = l1;
            slg[wave * 2    ] = q0 ? l0 : -1e30f;
            slg[wave * 2 + 1] = q1 ? l1 : -1e30f;
        }
        __syncthreads();
        if (t == 0) {
            float m = slg[0];
            #pragma unroll
            for (int i = 1; i < 8; ++i) m = fmaxf(m, slg[i]);
            float s2 = 0.f;
            #pragma unroll
            for (int i = 0; i < 8; ++i) s2 += expf(slg[i] - m);
            ws[O_PART + 2 * blockIdx.x]     = m;
            ws[O_PART + 2 * blockIdx.x + 1] = s2;
        }
    }
}

// ---- K2: combine partials -> lse (block-redundant, L2) + subtract ----
__global__ __launch_bounds__(1024) void k_logp(const float* __restrict__ ws,
        float* __restrict__ out) {
    const int t = threadIdx.x, lane = t & 63, wv = t >> 6;
    __shared__ float smm[16], sss[16];
    __shared__ float slse;
    float m = -1e30f, s = 0.f;
    for (int i = t; i < GRID; i += 1024) {
        float m2 = ws[O_PART + 2 * i], s2 = ws[O_PART + 2 * i + 1];
        float M = fmaxf(m, m2);
        s = s * expf(m - M) + s2 * expf(m2 - M);
        m = M;
    }
    for (int o = 32; o > 0; o >>= 1) {
        float m2 = __shfl_down(m, o, 64), s2 = __shfl_down(s, o, 64);
        float M = fmaxf(m, m2);
        s = s * expf(m - M) + s2 * expf(m2 - M);
        m = M;
    }
    if (lane == 0) { smm[wv] = m; sss[wv] = s; }
    __syncthreads();
    if (t == 0) {
        float M = smm[0], Ssum = sss[0];
        #pragma unroll
        for (int i = 1; i < 16; ++i) {
            float MM = fmaxf(M, smm[i]);
            Ssum = Ssum * expf(M - MM) + sss[i] * expf(smm[i] - MM);
            M = MM;
        }
        slse = M + logf(Ssum);
    }
    __syncthreads();
    const float lse = slse;
    int v = blockIdx.x * 1024 + t;
    if (v < V) out[v] = ws[O_LOGITS + v] - lse;
}

extern "C" void kernel_launch(void* const* d_in, const int* in_sizes, int n_in,
                              void* d_out, int out_size, void* d_ws, size_t ws_size,
                              hipStream_t stream) {
    const int*   ids    = (const int*)  d_in[0];
    const float* h0     = (const float*)d_in[1];
    const float* c0     = (const float*)d_in[2];
    const float* enc    = (const float*)d_in[3];
    const float* emb    = (const float*)d_in[4];
    const float* attn_W = (const float*)d_in[5];
    const float* attn_b = (const float*)d_in[6];
    const float* comb_W = (const float*)d_in[7];
    const float* comb_b = (const float*)d_in[8];
    const float* W_ih   = (const float*)d_in[9];
    const float* W_hh   = (const float*)d_in[10];
    const float* b_ih   = (const float*)d_in[11];
    const float* b_hh   = (const float*)d_in[12];
    const float* out_W  = (const float*)d_in[13];
    const float* out_b  = (const float*)d_in[14];
    float* out = (float*)d_out;
    float* ws  = (float*)d_ws;

    mega  <<<GRID, 256, 0, stream>>>(ids, h0, c0, enc, emb, attn_W, attn_b,
                                     comb_W, comb_b, W_ih, W_hh, b_ih, b_hh,
                                     out_W, out_b, out, ws);
    k_logp<<<64, 1024, 0, stream>>>(ws, out);
}

// Round 6
// 71.577 us; speedup vs baseline: 3.0920x; 3.0920x over previous
//
#include <hip/hip_runtime.h>
#include <math.h>

#define H 1024
#define V 50257
#define S 2048
#define NCH 128            // attention chunks (16 s-rows each)
#define NPART 3142         // ceil(V/16) logits blocks

// ws float offsets (16-float aligned)
#define O_CTXP   0                    // NCH*H = 131072
#define O_CTX    131072               // H
#define O_Z      132096               // H
#define O_GPRE   133120               // 4H  (W_hh@h0 + b_ih + b_hh)
#define O_HNEW   137216               // H
#define O_PART   138240               // 2*NPART

__device__ inline float wred_sum(float v) {
    for (int o = 32; o > 0; o >>= 1) v += __shfl_down(v, o, 64);
    return v;
}
__device__ inline float sigm(float x) { return 1.f / (1.f + expf(-x)); }
__device__ inline float dot4(float4 a, float4 b) {
    return a.x*b.x + a.y*b.y + a.z*b.z + a.w*b.w;
}

// ---- K1 (384 blocks): b<128: attn chunk (coeff + ctxp partial);
//      b>=128: gpre rows = W_hh@h0 + b_ih + b_hh  (input-only dependent) ----
__global__ __launch_bounds__(256) void k_attn(const float* __restrict__ enc,
        const float* __restrict__ h0, const float* __restrict__ attn_W,
        const float* __restrict__ attn_b, const float* __restrict__ W_hh,
        const float* __restrict__ b_ih, const float* __restrict__ b_hh,
        float* __restrict__ ws) {
    const int b = blockIdx.x, t = threadIdx.x, lane = t & 63, wave = t >> 6;
    if (b < NCH) {
        __shared__ float sred[4];
        __shared__ float scoef[16];
        // hdot = dot(h0, attn_W[H:2H]) + attn_b  (block-redundant, 8KB)
        float4 hv4 = ((const float4*)h0)[t];
        float4 wv4 = ((const float4*)(attn_W + H))[t];
        float p = wred_sum(dot4(hv4, wv4));
        if (lane == 0) sred[wave] = p;
        __syncthreads();
        const float hdot = sred[0] + sred[1] + sred[2] + sred[3] + attn_b[0];
        // coeff for 16 rows: wave handles 4 rows with 4 accumulators
        const float4* w0 = (const float4*)attn_W;
        const int s0 = b * 16;
        {
            int sb = s0 + wave * 4;
            const float4* e0 = (const float4*)(enc + (size_t)(sb    ) * H);
            const float4* e1 = (const float4*)(enc + (size_t)(sb + 1) * H);
            const float4* e2 = (const float4*)(enc + (size_t)(sb + 2) * H);
            const float4* e3 = (const float4*)(enc + (size_t)(sb + 3) * H);
            float a0 = 0.f, a1 = 0.f, a2 = 0.f, a3 = 0.f;
            #pragma unroll
            for (int kk = 0; kk < 4; ++kk) {
                int k4 = kk * 64 + lane;
                float4 w = w0[k4];
                a0 += dot4(e0[k4], w); a1 += dot4(e1[k4], w);
                a2 += dot4(e2[k4], w); a3 += dot4(e3[k4], w);
            }
            a0 = wred_sum(a0); a1 = wred_sum(a1);
            a2 = wred_sum(a2); a3 = wred_sum(a3);
            if (lane == 0) {
                scoef[wave*4 + 0] = a0 + hdot;
                scoef[wave*4 + 1] = a1 + hdot;
                scoef[wave*4 + 2] = a2 + hdot;
                scoef[wave*4 + 3] = a3 + hdot;
            }
        }
        __syncthreads();
        // ctxp[b][j] = sum over the 16 rows (rows are L2-hot from pass 1)
        float4 a4 = make_float4(0.f, 0.f, 0.f, 0.f);
        #pragma unroll 4
        for (int rr = 0; rr < 16; ++rr) {
            float c = scoef[rr];
            float4 e = ((const float4*)(enc + (size_t)(s0 + rr) * H))[t];
            a4.x += c * e.x; a4.y += c * e.y; a4.z += c * e.z; a4.w += c * e.w;
        }
        ((float4*)(ws + O_CTXP + b * H))[t] = a4;
    } else {
        // gpre: 16 gate-rows per block; wave handles 4 rows
        const int bb = b - NCH;            // 0..255
        float4 hr[4];
        #pragma unroll
        for (int kk = 0; kk < 4; ++kk) hr[kk] = ((const float4*)h0)[kk*64 + lane];
        const int r0 = bb * 16 + wave * 4;
        const float4* m0 = (const float4*)(W_hh + (size_t)(r0    ) * H);
        const float4* m1 = (const float4*)(W_hh + (size_t)(r0 + 1) * H);
        const float4* m2 = (const float4*)(W_hh + (size_t)(r0 + 2) * H);
        const float4* m3 = (const float4*)(W_hh + (size_t)(r0 + 3) * H);
        float a0 = 0.f, a1 = 0.f, a2 = 0.f, a3 = 0.f;
        #pragma unroll
        for (int kk = 0; kk < 4; ++kk) {
            int k4 = kk * 64 + lane;
            float4 a = hr[kk];
            a0 += dot4(m0[k4], a); a1 += dot4(m1[k4], a);
            a2 += dot4(m2[k4], a); a3 += dot4(m3[k4], a);
        }
        a0 = wred_sum(a0); a1 = wred_sum(a1);
        a2 = wred_sum(a2); a3 = wred_sum(a3);
        if (lane == 0) {
            ws[O_GPRE + r0    ] = a0 + b_ih[r0    ] + b_hh[r0    ];
            ws[O_GPRE + r0 + 1] = a1 + b_ih[r0 + 1] + b_hh[r0 + 1];
            ws[O_GPRE + r0 + 2] = a2 + b_ih[r0 + 2] + b_hh[r0 + 2];
            ws[O_GPRE + r0 + 3] = a3 + b_ih[r0 + 3] + b_hh[r0 + 3];
        }
    }
}

// ---- K2 (64 blocks): ctx[j] = sum_ch ctxp[ch][j], coalesced column slices ----
__global__ __launch_bounds__(256) void k_ctx(float* __restrict__ ws) {
    const int b = blockIdx.x, t = threadIdx.x;
    const int jj = t & 15, cg = t >> 4;     // 16 j x 16 chunk-groups
    const int j0 = b * 16;
    float acc = 0.f;
    #pragma unroll
    for (int k = 0; k < 8; ++k)
        acc += ws[O_CTXP + (size_t)(cg + 16*k) * H + j0 + jj];
    __shared__ float sarr[256];
    sarr[t] = acc;
    __syncthreads();
    if (t < 16) {
        float a = 0.f;
        #pragma unroll
        for (int g = 0; g < 16; ++g) a += sarr[g * 16 + t];
        ws[O_CTX + j0 + t] = a;
    }
}

// ---- K3 (256 blocks): z = relu(comb_W @ [x; ctx] + comb_b), wave per row ----
__global__ __launch_bounds__(256) void k_z(const float* __restrict__ emb,
        const int* __restrict__ ids, const float* __restrict__ comb_W,
        const float* __restrict__ comb_b, float* __restrict__ ws) {
    const int b = blockIdx.x, t = threadIdx.x, lane = t & 63, wave = t >> 6;
    const int tok = ids[0];
    const int i = b * 4 + wave;
    const float4* wrow = (const float4*)(comb_W + (size_t)i * 2 * H);
    const float4* x4 = (const float4*)(emb + (size_t)tok * H);
    const float4* c4 = (const float4*)(ws + O_CTX);
    float acc = 0.f;
    #pragma unroll
    for (int kk = 0; kk < 4; ++kk) {
        int k4 = kk * 64 + lane;
        acc += dot4(wrow[k4], x4[k4]);
        acc += dot4(wrow[256 + k4], c4[k4]);
    }
    acc = wred_sum(acc);
    if (lane == 0) ws[O_Z + i] = fmaxf(acc + comb_b[i], 0.f);
}

// ---- K4 (1024 blocks): gates = W_ih@z + gpre; LSTM pointwise; block = j ----
__global__ __launch_bounds__(256) void k_gates_lstm(const float* __restrict__ W_ih,
        const float* __restrict__ c0, float* __restrict__ ws, float* __restrict__ out) {
    const int j = blockIdx.x, t = threadIdx.x, lane = t & 63, g = t >> 6;
    __shared__ float sg[4];
    const int row = g * H + j;
    const float4* wi = (const float4*)(W_ih + (size_t)row * H);
    const float4* zv = (const float4*)(ws + O_Z);
    float acc = 0.f;
    #pragma unroll
    for (int kk = 0; kk < 4; ++kk) {
        int k4 = kk * 64 + lane;
        acc += dot4(wi[k4], zv[k4]);
    }
    acc = wred_sum(acc);
    if (lane == 0) sg[g] = acc + ws[O_GPRE + row];
    __syncthreads();
    if (t == 0) {
        float ig = sigm(sg[0]);
        float fg = sigm(sg[1]);
        float gg = tanhf(sg[2]);
        float og = sigm(sg[3]);
        float cn = fg * c0[j] + ig * gg;
        float hn = og * tanhf(cn);
        out[V + j]     = hn;
        out[V + H + j] = cn;
        ws[O_HNEW + j] = hn;
    }
}

// ---- K5 (NPART blocks): logits GEMV, 4 rows/wave ILP; raw logits -> out ----
__global__ __launch_bounds__(256) void k_logits(const float* __restrict__ out_W,
        const float* __restrict__ out_b, float* __restrict__ ws,
        float* __restrict__ out) {
    const int t = threadIdx.x, lane = t & 63, wave = t >> 6;
    __shared__ float slg[16];
    const float4* hv = (const float4*)(ws + O_HNEW);
    float4 hr[4];
    #pragma unroll
    for (int kk = 0; kk < 4; ++kk) hr[kk] = hv[kk * 64 + lane];
    const int v0 = blockIdx.x * 16 + wave * 4;
    const bool q0 = v0 < V, q1 = v0 + 1 < V, q2 = v0 + 2 < V, q3 = v0 + 3 < V;
    const float4* w0 = (const float4*)(out_W + (size_t)(q0 ? v0     : 0) * H);
    const float4* w1 = (const float4*)(out_W + (size_t)(q1 ? v0 + 1 : 0) * H);
    const float4* w2 = (const float4*)(out_W + (size_t)(q2 ? v0 + 2 : 0) * H);
    const float4* w3 = (const float4*)(out_W + (size_t)(q3 ? v0 + 3 : 0) * H);
    float a0 = 0.f, a1 = 0.f, a2 = 0.f, a3 = 0.f;
    #pragma unroll
    for (int kk = 0; kk < 4; ++kk) {
        int k4 = kk * 64 + lane;
        float4 a = hr[kk];
        a0 += dot4(w0[k4], a); a1 += dot4(w1[k4], a);
        a2 += dot4(w2[k4], a); a3 += dot4(w3[k4], a);
    }
    a0 = wred_sum(a0); a1 = wred_sum(a1);
    a2 = wred_sum(a2); a3 = wred_sum(a3);
    if (lane == 0) {
        float l0 = a0 + out_b[q0 ? v0     : 0];
        float l1 = a1 + out_b[q1 ? v0 + 1 : 0];
        float l2 = a2 + out_b[q2 ? v0 + 2 : 0];
        float l3 = a3 + out_b[q3 ? v0 + 3 : 0];
        if (q0) out[v0    ] = l0;
        if (q1) out[v0 + 1] = l1;
        if (q2) out[v0 + 2] = l2;
        if (q3) out[v0 + 3] = l3;
        slg[wave*4 + 0] = q0 ? l0 : -1e30f;
        slg[wave*4 + 1] = q1 ? l1 : -1e30f;
        slg[wave*4 + 2] = q2 ? l2 : -1e30f;
        slg[wave*4 + 3] = q3 ? l3 : -1e30f;
    }
    __syncthreads();
    if (t == 0) {
        float m = slg[0];
        #pragma unroll
        for (int i = 1; i < 16; ++i) m = fmaxf(m, slg[i]);
        float s = 0.f;
        #pragma unroll
        for (int i = 0; i < 16; ++i) s += expf(slg[i] - m);
        ws[O_PART + 2 * blockIdx.x]     = m;
        ws[O_PART + 2 * blockIdx.x + 1] = s;
    }
}

// ---- K6 (64 blocks): combine partials -> lse (block-redundant); out -= lse ----
__global__ __launch_bounds__(1024) void k_logp(const float* __restrict__ ws,
        float* __restrict__ out) {
    const int t = threadIdx.x, lane = t & 63, wv = t >> 6;
    __shared__ float smm[16], sss[16];
    __shared__ float slse;
    float m = -1e30f, s = 0.f;
    for (int i = t; i < NPART; i += 1024) {
        float m2 = ws[O_PART + 2 * i], s2 = ws[O_PART + 2 * i + 1];
        float M = fmaxf(m, m2);
        s = s * expf(m - M) + s2 * expf(m2 - M);
        m = M;
    }
    for (int o = 32; o > 0; o >>= 1) {
        float m2 = __shfl_down(m, o, 64), s2 = __shfl_down(s, o, 64);
        float M = fmaxf(m, m2);
        s = s * expf(m - M) + s2 * expf(m2 - M);
        m = M;
    }
    if (lane == 0) { smm[wv] = m; sss[wv] = s; }
    __syncthreads();
    if (t == 0) {
        float M = smm[0], Ssum = sss[0];
        #pragma unroll
        for (int i = 1; i < 16; ++i) {
            float MM = fmaxf(M, smm[i]);
            Ssum = Ssum * expf(M - MM) + sss[i] * expf(smm[i] - MM);
            M = MM;
        }
        slse = M + logf(Ssum);
    }
    __syncthreads();
    const float lse = slse;
    const int v = blockIdx.x * 1024 + t;
    if (v < V) out[v] = out[v] - lse;
}

extern "C" void kernel_launch(void* const* d_in, const int* in_sizes, int n_in,
                              void* d_out, int out_size, void* d_ws, size_t ws_size,
                              hipStream_t stream) {
    const int*   ids    = (const int*)  d_in[0];
    const float* h0     = (const float*)d_in[1];
    const float* c0     = (const float*)d_in[2];
    const float* enc    = (const float*)d_in[3];
    const float* emb    = (const float*)d_in[4];
    const float* attn_W = (const float*)d_in[5];
    const float* attn_b = (const float*)d_in[6];
    const float* comb_W = (const float*)d_in[7];
    const float* comb_b = (const float*)d_in[8];
    const float* W_ih   = (const float*)d_in[9];
    const float* W_hh   = (const float*)d_in[10];
    const float* b_ih   = (const float*)d_in[11];
    const float* b_hh   = (const float*)d_in[12];
    const float* out_W  = (const float*)d_in[13];
    const float* out_b  = (const float*)d_in[14];
    float* out = (float*)d_out;
    float* ws  = (float*)d_ws;

    k_attn      <<<NCH + 256, 256, 0, stream>>>(enc, h0, attn_W, attn_b,
                                                W_hh, b_ih, b_hh, ws);
    k_ctx       <<<64, 256, 0, stream>>>(ws);
    k_z         <<<256, 256, 0, stream>>>(emb, ids, comb_W, comb_b, ws);
    k_gates_lstm<<<1024, 256, 0, stream>>>(W_ih, c0, ws, out);
    k_logits    <<<NPART, 256, 0, stream>>>(out_W, out_b, ws, out);
    k_logp      <<<64, 1024, 0, stream>>>(ws, out);
}

// Round 7
// 70.822 us; speedup vs baseline: 3.1250x; 1.0107x over previous
//
#include <hip/hip_runtime.h>
#include <math.h>

#define H 1024
#define V 50257
#define S 2048
#define NCH 32             // attention chunks (64 s-rows each)
#define LROWS 32           // logit rows per block
#define NPART 1571         // ceil(V/32) logits blocks

// ws float offsets (16-float aligned)
#define O_CTXP   0                    // NCH*H = 32768
#define O_Z      32768                // H
#define O_GPRE   33792                // 4H  (W_hh@h0 + b_ih + b_hh)
#define O_HNEW   37888                // H
#define O_PART   38912                // 2*NPART

__device__ inline float wred_sum(float v) {
    for (int o = 32; o > 0; o >>= 1) v += __shfl_down(v, o, 64);
    return v;
}
__device__ inline float sigm(float x) { return 1.f / (1.f + expf(-x)); }
__device__ inline float dot4(float4 a, float4 b) {
    return a.x*b.x + a.y*b.y + a.z*b.z + a.w*b.w;
}

// ---- K1 (NCH+256 blocks): b<NCH: attn chunk (coeff + ctxp partial);
//      b>=NCH: gpre rows = W_hh@h0 + b_ih + b_hh ----
__global__ __launch_bounds__(256) void k_attn(const float* __restrict__ enc,
        const float* __restrict__ h0, const float* __restrict__ attn_W,
        const float* __restrict__ attn_b, const float* __restrict__ W_hh,
        const float* __restrict__ b_ih, const float* __restrict__ b_hh,
        float* __restrict__ ws) {
    const int b = blockIdx.x, t = threadIdx.x, lane = t & 63, wave = t >> 6;
    if (b < NCH) {
        __shared__ float sred[4];
        __shared__ float scoef[64];
        // hdot = dot(h0, attn_W[H:2H]) + attn_b  (block-redundant, 8KB)
        float4 hv4 = ((const float4*)h0)[t];
        float4 wv4 = ((const float4*)(attn_W + H))[t];
        float p = wred_sum(dot4(hv4, wv4));
        if (lane == 0) sred[wave] = p;
        __syncthreads();
        const float hdot = sred[0] + sred[1] + sred[2] + sred[3] + attn_b[0];
        // coeff for 64 rows: wave handles 16 rows, 4 at a time (ILP 4)
        const float4* w0 = (const float4*)attn_W;
        const int s0 = b * 64;
        #pragma unroll
        for (int gq = 0; gq < 4; ++gq) {
            int sb = s0 + wave * 16 + gq * 4;
            const float4* e0 = (const float4*)(enc + (size_t)(sb    ) * H);
            const float4* e1 = (const float4*)(enc + (size_t)(sb + 1) * H);
            const float4* e2 = (const float4*)(enc + (size_t)(sb + 2) * H);
            const float4* e3 = (const float4*)(enc + (size_t)(sb + 3) * H);
            float a0 = 0.f, a1 = 0.f, a2 = 0.f, a3 = 0.f;
            #pragma unroll
            for (int kk = 0; kk < 4; ++kk) {
                int k4 = kk * 64 + lane;
                float4 w = w0[k4];
                a0 += dot4(e0[k4], w); a1 += dot4(e1[k4], w);
                a2 += dot4(e2[k4], w); a3 += dot4(e3[k4], w);
            }
            a0 = wred_sum(a0); a1 = wred_sum(a1);
            a2 = wred_sum(a2); a3 = wred_sum(a3);
            if (lane == 0) {
                scoef[wave*16 + gq*4 + 0] = a0 + hdot;
                scoef[wave*16 + gq*4 + 1] = a1 + hdot;
                scoef[wave*16 + gq*4 + 2] = a2 + hdot;
                scoef[wave*16 + gq*4 + 3] = a3 + hdot;
            }
        }
        __syncthreads();
        // ctxp[b][j] = sum over the 64 rows (rows L2-hot from pass 1)
        float4 a4 = make_float4(0.f, 0.f, 0.f, 0.f);
        #pragma unroll 8
        for (int rr = 0; rr < 64; ++rr) {
            float c = scoef[rr];
            float4 e = ((const float4*)(enc + (size_t)(s0 + rr) * H))[t];
            a4.x += c * e.x; a4.y += c * e.y; a4.z += c * e.z; a4.w += c * e.w;
        }
        ((float4*)(ws + O_CTXP + b * H))[t] = a4;
    } else {
        // gpre: 16 gate-rows per block; wave handles 4 rows (ILP 4)
        const int bb = b - NCH;            // 0..255
        float4 hr[4];
        #pragma unroll
        for (int kk = 0; kk < 4; ++kk) hr[kk] = ((const float4*)h0)[kk*64 + lane];
        const int r0 = bb * 16 + wave * 4;
        const float4* m0 = (const float4*)(W_hh + (size_t)(r0    ) * H);
        const float4* m1 = (const float4*)(W_hh + (size_t)(r0 + 1) * H);
        const float4* m2 = (const float4*)(W_hh + (size_t)(r0 + 2) * H);
        const float4* m3 = (const float4*)(W_hh + (size_t)(r0 + 3) * H);
        float a0 = 0.f, a1 = 0.f, a2 = 0.f, a3 = 0.f;
        #pragma unroll
        for (int kk = 0; kk < 4; ++kk) {
            int k4 = kk * 64 + lane;
            float4 a = hr[kk];
            a0 += dot4(m0[k4], a); a1 += dot4(m1[k4], a);
            a2 += dot4(m2[k4], a); a3 += dot4(m3[k4], a);
        }
        a0 = wred_sum(a0); a1 = wred_sum(a1);
        a2 = wred_sum(a2); a3 = wred_sum(a3);
        if (lane == 0) {
            ws[O_GPRE + r0    ] = a0 + b_ih[r0    ] + b_hh[r0    ];
            ws[O_GPRE + r0 + 1] = a1 + b_ih[r0 + 1] + b_hh[r0 + 1];
            ws[O_GPRE + r0 + 2] = a2 + b_ih[r0 + 2] + b_hh[r0 + 2];
            ws[O_GPRE + r0 + 3] = a3 + b_ih[r0 + 3] + b_hh[r0 + 3];
        }
    }
}

// ---- K2 (256 blocks): ctx reduce (block-redundant, 128KB) + z rows ----
__global__ __launch_bounds__(256) void k_z(const float* __restrict__ emb,
        const int* __restrict__ ids, const float* __restrict__ comb_W,
        const float* __restrict__ comb_b, float* __restrict__ ws) {
    const int b = blockIdx.x, t = threadIdx.x, lane = t & 63, wave = t >> 6;
    __shared__ __align__(16) float sctx[H];
    float4 a4 = make_float4(0.f, 0.f, 0.f, 0.f);
    #pragma unroll 8
    for (int ch = 0; ch < NCH; ++ch) {
        float4 v = ((const float4*)(ws + O_CTXP + ch * H))[t];
        a4.x += v.x; a4.y += v.y; a4.z += v.z; a4.w += v.w;
    }
    ((float4*)sctx)[t] = a4;
    __syncthreads();

    const int tok = ids[0];
    const int i = b * 4 + wave;
    const float4* wrow = (const float4*)(comb_W + (size_t)i * 2 * H);
    const float4* x4 = (const float4*)(emb + (size_t)tok * H);
    const float4* c4 = (const float4*)sctx;
    float acc = 0.f;
    #pragma unroll
    for (int kk = 0; kk < 4; ++kk) {
        int k4 = kk * 64 + lane;
        acc += dot4(wrow[k4], x4[k4]);
        acc += dot4(wrow[256 + k4], c4[k4]);
    }
    acc = wred_sum(acc);
    if (lane == 0) ws[O_Z + i] = fmaxf(acc + comb_b[i], 0.f);
}

// ---- K3 (1024 blocks): gates = W_ih@z + gpre; LSTM pointwise; block = j ----
__global__ __launch_bounds__(256) void k_gates_lstm(const float* __restrict__ W_ih,
        const float* __restrict__ c0, float* __restrict__ ws, float* __restrict__ out) {
    const int j = blockIdx.x, t = threadIdx.x, lane = t & 63, g = t >> 6;
    __shared__ float sg[4];
    const int row = g * H + j;
    const float4* wi = (const float4*)(W_ih + (size_t)row * H);
    const float4* zv = (const float4*)(ws + O_Z);
    float acc = 0.f;
    #pragma unroll
    for (int kk = 0; kk < 4; ++kk) {
        int k4 = kk * 64 + lane;
        acc += dot4(wi[k4], zv[k4]);
    }
    acc = wred_sum(acc);
    if (lane == 0) sg[g] = acc + ws[O_GPRE + row];
    __syncthreads();
    if (t == 0) {
        float ig = sigm(sg[0]);
        float fg = sigm(sg[1]);
        float gg = tanhf(sg[2]);
        float og = sigm(sg[3]);
        float cn = fg * c0[j] + ig * gg;
        float hn = og * tanhf(cn);
        out[V + j]     = hn;
        out[V + H + j] = cn;
        ws[O_HNEW + j] = hn;
    }
}

// ---- K4 (NPART blocks x 512): logits GEMV, 4 rows/wave ILP, raw -> out ----
__global__ __launch_bounds__(512) void k_logits(const float* __restrict__ out_W,
        const float* __restrict__ out_b, float* __restrict__ ws,
        float* __restrict__ out) {
    const int t = threadIdx.x, lane = t & 63, wave = t >> 6;   // 8 waves
    __shared__ float slg[32];
    const float4* hv = (const float4*)(ws + O_HNEW);
    float4 hr[4];
    #pragma unroll
    for (int kk = 0; kk < 4; ++kk) hr[kk] = hv[kk * 64 + lane];
    const int v0 = blockIdx.x * LROWS + wave * 4;
    const bool q0 = v0 < V, q1 = v0 + 1 < V, q2 = v0 + 2 < V, q3 = v0 + 3 < V;
    const float4* w0 = (const float4*)(out_W + (size_t)(q0 ? v0     : 0) * H);
    const float4* w1 = (const float4*)(out_W + (size_t)(q1 ? v0 + 1 : 0) * H);
    const float4* w2 = (const float4*)(out_W + (size_t)(q2 ? v0 + 2 : 0) * H);
    const float4* w3 = (const float4*)(out_W + (size_t)(q3 ? v0 + 3 : 0) * H);
    float a0 = 0.f, a1 = 0.f, a2 = 0.f, a3 = 0.f;
    #pragma unroll
    for (int kk = 0; kk < 4; ++kk) {
        int k4 = kk * 64 + lane;
        float4 a = hr[kk];
        a0 += dot4(w0[k4], a); a1 += dot4(w1[k4], a);
        a2 += dot4(w2[k4], a); a3 += dot4(w3[k4], a);
    }
    a0 = wred_sum(a0); a1 = wred_sum(a1);
    a2 = wred_sum(a2); a3 = wred_sum(a3);
    if (lane == 0) {
        float l0 = a0 + out_b[q0 ? v0     : 0];
        float l1 = a1 + out_b[q1 ? v0 + 1 : 0];
        float l2 = a2 + out_b[q2 ? v0 + 2 : 0];
        float l3 = a3 + out_b[q3 ? v0 + 3 : 0];
        if (q0) out[v0    ] = l0;
        if (q1) out[v0 + 1] = l1;
        if (q2) out[v0 + 2] = l2;
        if (q3) out[v0 + 3] = l3;
        slg[wave*4 + 0] = q0 ? l0 : -1e30f;
        slg[wave*4 + 1] = q1 ? l1 : -1e30f;
        slg[wave*4 + 2] = q2 ? l2 : -1e30f;
        slg[wave*4 + 3] = q3 ? l3 : -1e30f;
    }
    __syncthreads();
    if (t == 0) {
        float m = slg[0];
        #pragma unroll
        for (int i = 1; i < 32; ++i) m = fmaxf(m, slg[i]);
        float s = 0.f;
        #pragma unroll
        for (int i = 0; i < 32; ++i) s += expf(slg[i] - m);
        ws[O_PART + 2 * blockIdx.x]     = m;
        ws[O_PART + 2 * blockIdx.x + 1] = s;
    }
}

// ---- K5 (64 blocks): combine partials -> lse (block-redundant); out -= lse ----
__global__ __launch_bounds__(1024) void k_logp(const float* __restrict__ ws,
        float* __restrict__ out) {
    const int t = threadIdx.x, lane = t & 63, wv = t >> 6;
    __shared__ float smm[16], sss[16];
    __shared__ float slse;
    float m = -1e30f, s = 0.f;
    for (int i = t; i < NPART; i += 1024) {
        float m2 = ws[O_PART + 2 * i], s2 = ws[O_PART + 2 * i + 1];
        float M = fmaxf(m, m2);
        s = s * expf(m - M) + s2 * expf(m2 - M);
        m = M;
    }
    for (int o = 32; o > 0; o >>= 1) {
        float m2 = __shfl_down(m, o, 64), s2 = __shfl_down(s, o, 64);
        float M = fmaxf(m, m2);
        s = s * expf(m - M) + s2 * expf(m2 - M);
        m = M;
    }
    if (lane == 0) { smm[wv] = m; sss[wv] = s; }
    __syncthreads();
    if (t == 0) {
        float M = smm[0], Ssum = sss[0];
        #pragma unroll
        for (int i = 1; i < 16; ++i) {
            float MM = fmaxf(M, smm[i]);
            Ssum = Ssum * expf(M - MM) + sss[i] * expf(smm[i] - MM);
            M = MM;
        }
        slse = M + logf(Ssum);
    }
    __syncthreads();
    const float lse = slse;
    const int v = blockIdx.x * 1024 + t;
    if (v < V) out[v] = out[v] - lse;
}

extern "C" void kernel_launch(void* const* d_in, const int* in_sizes, int n_in,
                              void* d_out, int out_size, void* d_ws, size_t ws_size,
                              hipStream_t stream) {
    const int*   ids    = (const int*)  d_in[0];
    const float* h0     = (const float*)d_in[1];
    const float* c0     = (const float*)d_in[2];
    const float* enc    = (const float*)d_in[3];
    const float* emb    = (const float*)d_in[4];
    const float* attn_W = (const float*)d_in[5];
    const float* attn_b = (const float*)d_in[6];
    const float* comb_W = (const float*)d_in[7];
    const float* comb_b = (const float*)d_in[8];
    const float* W_ih   = (const float*)d_in[9];
    const float* W_hh   = (const float*)d_in[10];
    const float* b_ih   = (const float*)d_in[11];
    const float* b_hh   = (const float*)d_in[12];
    const float* out_W  = (const float*)d_in[13];
    const float* out_b  = (const float*)d_in[14];
    float* out = (float*)d_out;
    float* ws  = (float*)d_ws;

    k_attn      <<<NCH + 256, 256, 0, stream>>>(enc, h0, attn_W, attn_b,
                                                W_hh, b_ih, b_hh, ws);
    k_z         <<<256, 256, 0, stream>>>(emb, ids, comb_W, comb_b, ws);
    k_gates_lstm<<<1024, 256, 0, stream>>>(W_ih, c0, ws, out);
    k_logits    <<<NPART, 512, 0, stream>>>(out_W, out_b, ws, out);
    k_logp      <<<64, 1024, 0, stream>>>(ws, out);
}

// Round 8
// 63.232 us; speedup vs baseline: 3.5000x; 1.1200x over previous
//
#include <hip/hip_runtime.h>
#include <math.h>

#define H 1024
#define V 50257
#define S 2048
#define NCH 128            // attention chunks (16 s-rows each)
#define NLOG 6283          // logits blocks (8 rows each)

// ws float offsets (16-float aligned)
#define O_CTXP   0                    // NCH*H = 131072
#define O_Z      131072               // H
#define O_GPRE   132096               // 4H  (W_hh@h0 + b_ih + b_hh)
#define O_HNEW   136192               // H
#define O_PART   137216               // 2*NLOG

__device__ inline float wred_sum(float v) {
    for (int o = 32; o > 0; o >>= 1) v += __shfl_down(v, o, 64);
    return v;
}
__device__ inline float sigm(float x) { return 1.f / (1.f + expf(-x)); }
__device__ inline float dot4(float4 a, float4 b) {
    return a.x*b.x + a.y*b.y + a.z*b.z + a.w*b.w;
}

// ---- K1 (NCH+256 blocks): b<NCH: attn chunk (coeff + ctxp partial, 16 rows);
//      b>=NCH: gpre rows = W_hh@h0 + b_ih + b_hh ----
__global__ __launch_bounds__(256) void k_attn(const float* __restrict__ enc,
        const float* __restrict__ h0, const float* __restrict__ attn_W,
        const float* __restrict__ attn_b, const float* __restrict__ W_hh,
        const float* __restrict__ b_ih, const float* __restrict__ b_hh,
        float* __restrict__ ws) {
    const int b = blockIdx.x, t = threadIdx.x, lane = t & 63, wave = t >> 6;
    if (b < NCH) {
        __shared__ float sred[4];
        __shared__ float scoef[16];
        // hdot = dot(h0, attn_W[H:2H]) + attn_b  (block-redundant, 8KB)
        float4 hv4 = ((const float4*)h0)[t];
        float4 wv4 = ((const float4*)(attn_W + H))[t];
        float p = wred_sum(dot4(hv4, wv4));
        if (lane == 0) sred[wave] = p;
        __syncthreads();
        const float hdot = sred[0] + sred[1] + sred[2] + sred[3] + attn_b[0];
        // coeff: wave owns 4 rows (ILP 4)
        const float4* w0 = (const float4*)attn_W;
        const int s0 = b * 16;
        {
            int sb = s0 + wave * 4;
            const float4* e0 = (const float4*)(enc + (size_t)(sb    ) * H);
            const float4* e1 = (const float4*)(enc + (size_t)(sb + 1) * H);
            const float4* e2 = (const float4*)(enc + (size_t)(sb + 2) * H);
            const float4* e3 = (const float4*)(enc + (size_t)(sb + 3) * H);
            float a0 = 0.f, a1 = 0.f, a2 = 0.f, a3 = 0.f;
            #pragma unroll
            for (int kk = 0; kk < 4; ++kk) {
                int k4 = kk * 64 + lane;
                float4 w = w0[k4];
                a0 += dot4(e0[k4], w); a1 += dot4(e1[k4], w);
                a2 += dot4(e2[k4], w); a3 += dot4(e3[k4], w);
            }
            a0 = wred_sum(a0); a1 = wred_sum(a1);
            a2 = wred_sum(a2); a3 = wred_sum(a3);
            if (lane == 0) {
                scoef[wave*4 + 0] = a0 + hdot;
                scoef[wave*4 + 1] = a1 + hdot;
                scoef[wave*4 + 2] = a2 + hdot;
                scoef[wave*4 + 3] = a3 + hdot;
            }
        }
        __syncthreads();
        // ctxp[b][j]: 2nd pass over the 16 rows (L2-hot)
        float4 a4 = make_float4(0.f, 0.f, 0.f, 0.f);
        #pragma unroll 4
        for (int rr = 0; rr < 16; ++rr) {
            float c = scoef[rr];
            float4 e = ((const float4*)(enc + (size_t)(s0 + rr) * H))[t];
            a4.x += c * e.x; a4.y += c * e.y; a4.z += c * e.z; a4.w += c * e.w;
        }
        ((float4*)(ws + O_CTXP + b * H))[t] = a4;
    } else {
        // gpre: 16 gate-rows per block; wave owns 4 rows (ILP 4)
        const int bb = b - NCH;            // 0..255
        float4 hr[4];
        #pragma unroll
        for (int kk = 0; kk < 4; ++kk) hr[kk] = ((const float4*)h0)[kk*64 + lane];
        const int r0 = bb * 16 + wave * 4;
        const float4* m0 = (const float4*)(W_hh + (size_t)(r0    ) * H);
        const float4* m1 = (const float4*)(W_hh + (size_t)(r0 + 1) * H);
        const float4* m2 = (const float4*)(W_hh + (size_t)(r0 + 2) * H);
        const float4* m3 = (const float4*)(W_hh + (size_t)(r0 + 3) * H);
        float a0 = 0.f, a1 = 0.f, a2 = 0.f, a3 = 0.f;
        #pragma unroll
        for (int kk = 0; kk < 4; ++kk) {
            int k4 = kk * 64 + lane;
            float4 a = hr[kk];
            a0 += dot4(m0[k4], a); a1 += dot4(m1[k4], a);
            a2 += dot4(m2[k4], a); a3 += dot4(m3[k4], a);
        }
        a0 = wred_sum(a0); a1 = wred_sum(a1);
        a2 = wred_sum(a2); a3 = wred_sum(a3);
        if (lane == 0) {
            ws[O_GPRE + r0    ] = a0 + b_ih[r0    ] + b_hh[r0    ];
            ws[O_GPRE + r0 + 1] = a1 + b_ih[r0 + 1] + b_hh[r0 + 1];
            ws[O_GPRE + r0 + 2] = a2 + b_ih[r0 + 2] + b_hh[r0 + 2];
            ws[O_GPRE + r0 + 3] = a3 + b_ih[r0 + 3] + b_hh[r0 + 3];
        }
    }
}

// ---- K2 (64 blocks x 512): ctx reduce (split across thread-halves) + 16 z rows ----
__global__ __launch_bounds__(512) void k_z(const float* __restrict__ emb,
        const int* __restrict__ ids, const float* __restrict__ comb_W,
        const float* __restrict__ comb_b, float* __restrict__ ws) {
    const int b = blockIdx.x, t = threadIdx.x, lane = t & 63, wave = t >> 6;
    __shared__ __align__(16) float spart[2][H];
    __shared__ __align__(16) float sctx[H];
    // reduce: half 0 sums chunks 0..63, half 1 sums 64..127, over float4 slot fi
    {
        const int half = t >> 8, fi = t & 255;
        float4 a4 = make_float4(0.f, 0.f, 0.f, 0.f);
        #pragma unroll 8
        for (int ch = half * 64; ch < half * 64 + 64; ++ch) {
            float4 v = ((const float4*)(ws + O_CTXP + ch * H))[fi];
            a4.x += v.x; a4.y += v.y; a4.z += v.z; a4.w += v.w;
        }
        ((float4*)spart[half])[fi] = a4;
    }
    __syncthreads();
    if (t < 256) {
        float4 p0 = ((const float4*)spart[0])[t];
        float4 p1 = ((const float4*)spart[1])[t];
        p0.x += p1.x; p0.y += p1.y; p0.z += p1.z; p0.w += p1.w;
        ((float4*)sctx)[t] = p0;
    }
    __syncthreads();

    const int tok = ids[0];
    const float4* x4 = (const float4*)(emb + (size_t)tok * H);
    const float4* c4 = (const float4*)sctx;
    // 8 waves x 2 rows (ILP 2): i = b*16 + wave*2 + {0,1}
    const int i0 = b * 16 + wave * 2;
    const float4* wr0 = (const float4*)(comb_W + (size_t)i0 * 2 * H);
    const float4* wr1 = (const float4*)(comb_W + (size_t)(i0 + 1) * 2 * H);
    float a0 = 0.f, a1 = 0.f;
    #pragma unroll
    for (int kk = 0; kk < 4; ++kk) {
        int k4 = kk * 64 + lane;
        float4 xv = x4[k4], cv = c4[k4];
        a0 += dot4(wr0[k4], xv) + dot4(wr0[256 + k4], cv);
        a1 += dot4(wr1[k4], xv) + dot4(wr1[256 + k4], cv);
    }
    a0 = wred_sum(a0); a1 = wred_sum(a1);
    if (lane == 0) {
        ws[O_Z + i0    ] = fmaxf(a0 + comb_b[i0    ], 0.f);
        ws[O_Z + i0 + 1] = fmaxf(a1 + comb_b[i0 + 1], 0.f);
    }
}

// ---- K3 (1024 blocks): gates = W_ih@z + gpre; LSTM pointwise; block = j ----
__global__ __launch_bounds__(256) void k_gates_lstm(const float* __restrict__ W_ih,
        const float* __restrict__ c0, float* __restrict__ ws, float* __restrict__ out) {
    const int j = blockIdx.x, t = threadIdx.x, lane = t & 63, g = t >> 6;
    __shared__ float sg[4];
    const int row = g * H + j;
    const float4* wi = (const float4*)(W_ih + (size_t)row * H);
    const float4* zv = (const float4*)(ws + O_Z);
    float acc = 0.f;
    #pragma unroll
    for (int kk = 0; kk < 4; ++kk) {
        int k4 = kk * 64 + lane;
        acc += dot4(wi[k4], zv[k4]);
    }
    acc = wred_sum(acc);
    if (lane == 0) sg[g] = acc + ws[O_GPRE + row];
    __syncthreads();
    if (t == 0) {
        float ig = sigm(sg[0]);
        float fg = sigm(sg[1]);
        float gg = tanhf(sg[2]);
        float og = sigm(sg[3]);
        float cn = fg * c0[j] + ig * gg;
        float hn = og * tanhf(cn);
        out[V + j]     = hn;
        out[V + H + j] = cn;
        ws[O_HNEW + j] = hn;
    }
}

// ---- K4 (NLOG blocks x 512): logits GEMV, wave per row; raw logits -> out ----
__global__ __launch_bounds__(512) void k_logits(const float* __restrict__ out_W,
        const float* __restrict__ out_b, float* __restrict__ ws,
        float* __restrict__ out) {
    const int t = threadIdx.x, lane = t & 63, wave = t >> 6;   // 8 waves
    __shared__ float slg[8];
    const float4* hv = (const float4*)(ws + O_HNEW);
    float4 hr[4];
    #pragma unroll
    for (int kk = 0; kk < 4; ++kk) hr[kk] = hv[kk * 64 + lane];
    const int v = blockIdx.x * 8 + wave;
    const bool q = v < V;
    const float4* wr = (const float4*)(out_W + (size_t)(q ? v : 0) * H);
    float acc = 0.f;
    #pragma unroll
    for (int kk = 0; kk < 4; ++kk) {
        int k4 = kk * 64 + lane;
        acc += dot4(wr[k4], hr[kk]);
    }
    acc = wred_sum(acc);
    if (lane == 0) {
        float lg = acc + out_b[q ? v : 0];
        if (q) out[v] = lg;
        slg[wave] = q ? lg : -1e30f;
    }
    __syncthreads();
    if (t == 0) {
        float m = slg[0];
        #pragma unroll
        for (int i = 1; i < 8; ++i) m = fmaxf(m, slg[i]);
        float s = 0.f;
        #pragma unroll
        for (int i = 0; i < 8; ++i) s += expf(slg[i] - m);
        ws[O_PART + 2 * blockIdx.x]     = m;
        ws[O_PART + 2 * blockIdx.x + 1] = s;
    }
}

// ---- K5 (64 blocks x 1024): combine partials -> lse (redundant); out -= lse ----
__global__ __launch_bounds__(1024) void k_logp(const float* __restrict__ ws,
        float* __restrict__ out) {
    const int t = threadIdx.x, lane = t & 63, wv = t >> 6;
    __shared__ float smm[16], sss[16];
    __shared__ float slse;
    float m = -1e30f, s = 0.f;
    for (int i = t; i < NLOG; i += 1024) {
        float m2 = ws[O_PART + 2 * i], s2 = ws[O_PART + 2 * i + 1];
        float M = fmaxf(m, m2);
        s = s * expf(m - M) + s2 * expf(m2 - M);
        m = M;
    }
    for (int o = 32; o > 0; o >>= 1) {
        float m2 = __shfl_down(m, o, 64), s2 = __shfl_down(s, o, 64);
        float M = fmaxf(m, m2);
        s = s * expf(m - M) + s2 * expf(m2 - M);
        m = M;
    }
    if (lane == 0) { smm[wv] = m; sss[wv] = s; }
    __syncthreads();
    if (t == 0) {
        float M = smm[0], Ssum = sss[0];
        #pragma unroll
        for (int i = 1; i < 16; ++i) {
            float MM = fmaxf(M, smm[i]);
            Ssum = Ssum * expf(M - MM) + sss[i] * expf(smm[i] - MM);
            M = MM;
        }
        slse = M + logf(Ssum);
    }
    __syncthreads();
    const float lse = slse;
    const int v = blockIdx.x * 1024 + t;
    if (v < V) out[v] = out[v] - lse;
}

extern "C" void kernel_launch(void* const* d_in, const int* in_sizes, int n_in,
                              void* d_out, int out_size, void* d_ws, size_t ws_size,
                              hipStream_t stream) {
    const int*   ids    = (const int*)  d_in[0];
    const float* h0     = (const float*)d_in[1];
    const float* c0     = (const float*)d_in[2];
    const float* enc    = (const float*)d_in[3];
    const float* emb    = (const float*)d_in[4];
    const float* attn_W = (const float*)d_in[5];
    const float* attn_b = (const float*)d_in[6];
    const float* comb_W = (const float*)d_in[7];
    const float* comb_b = (const float*)d_in[8];
    const float* W_ih   = (const float*)d_in[9];
    const float* W_hh   = (const float*)d_in[10];
    const float* b_ih   = (const float*)d_in[11];
    const float* b_hh   = (const float*)d_in[12];
    const float* out_W  = (const float*)d_in[13];
    const float* out_b  = (const float*)d_in[14];
    float* out = (float*)d_out;
    float* ws  = (float*)d_ws;

    k_attn      <<<NCH + 256, 256, 0, stream>>>(enc, h0, attn_W, attn_b,
                                                W_hh, b_ih, b_hh, ws);
    k_z         <<<64, 512, 0, stream>>>(emb, ids, comb_W, comb_b, ws);
    k_gates_lstm<<<1024, 256, 0, stream>>>(W_ih, c0, ws, out);
    k_logits    <<<NLOG, 512, 0, stream>>>(out_W, out_b, ws, out);
    k_logp      <<<64, 1024, 0, stream>>>(ws, out);
}